// Round 2
// baseline (379.047 us; speedup 1.0000x reference)
//
#include <hip/hip_runtime.h>
#include <hip/hip_bf16.h>
#include <hip/hip_fp16.h>

#define B_ 8
#define N_ 1024
#define D_ 256
#define H_ 8
#define HD_ 512   // H_*64

typedef _Float16 f16;
typedef _Float16 f16x8 __attribute__((ext_vector_type(8)));
typedef _Float16 f16x4 __attribute__((ext_vector_type(4)));
typedef float f32x4 __attribute__((ext_vector_type(4)));
typedef unsigned long long ull;
typedef unsigned long long ull2 __attribute__((ext_vector_type(2)));

// ---------------------------------------------------------------------------
// Pre-kernel A: bit-pack edge mask.  mask (B,N,N) f32 -> bmT[b][tt][row] u64
// where bit t of bmT[b][tt][row] = (mask[b][row][tt*64+t] != 0).
// One wave per row; 16 ballots.
// ---------------------------------------------------------------------------
__global__ __launch_bounds__(256) void pack_mask_kernel(
    const float* __restrict__ mask, ull* __restrict__ bmT)
{
    const int wv = threadIdx.x >> 6, lane = threadIdx.x & 63;
    const int r = blockIdx.x * 4 + wv;          // 0..8191
    const int b = r >> 10, n = r & 1023;
    const float* row = mask + ((size_t)b * N_ + n) * N_;
    for (int tt = 0; tt < 16; ++tt) {
        float v = row[tt * 64 + lane];
        ull m = __ballot(v != 0.0f);
        if (lane == 0) bmT[((size_t)b * 16 + tt) * N_ + n] = m;
    }
}

// ---------------------------------------------------------------------------
// Pre-kernel B: WTqkv[c][k] = f16( W{q|k|v}[k][c&511] ),  c in [0,1536)
// ---------------------------------------------------------------------------
__global__ __launch_bounds__(256) void wconv_qkv_kernel(
    const float* __restrict__ Wq, const float* __restrict__ Wk,
    const float* __restrict__ Wv, f16* __restrict__ WT)
{
    const int c = blockIdx.x, k = threadIdx.x;
    const int m = c >> 9, cw = c & 511;
    const float* Wsel = (m == 0) ? Wq : (m == 1) ? Wk : Wv;
    WT[(size_t)c * D_ + k] = (f16)Wsel[(size_t)k * HD_ + cw];
}

// ---------------------------------------------------------------------------
// Pre-kernel C: WToT[c][k] = f16( Wo[k][c] ),  c in [0,256), k in [0,512)
// ---------------------------------------------------------------------------
__global__ __launch_bounds__(256) void wconv_o_kernel(
    const float* __restrict__ Wo, f16* __restrict__ WToT)
{
    const int c = blockIdx.x;
    for (int k = threadIdx.x; k < HD_; k += 256)
        WToT[(size_t)c * HD_ + k] = (f16)Wo[(size_t)k * D_ + c];
}

// ---------------------------------------------------------------------------
// Kernel 1: fused QKV projection, no LDS.  B-fragments straight from WTqkv.
// Block: 64 rows x 256 cols, 4 waves; wave = 16 rows x 256 cols.
// ---------------------------------------------------------------------------
__global__ __launch_bounds__(256) void qkv_kernel(
    const float* __restrict__ X, const f16* __restrict__ WT,
    f16* __restrict__ Qh, f16* __restrict__ Kh, f16* __restrict__ Vt)
{
    const int tid = threadIdx.x;
    const int wv = tid >> 6, lane = tid & 63;
    const int g = lane >> 4, li = lane & 15;
    const int row0 = blockIdx.x * 64;
    const int c0 = blockIdx.y * 256;
    const int m = c0 >> 9;                 // 0=Q,1=K,2=V
    const int cw0 = c0 & 511;

    f32x4 acc[16] = {};
    const float* Xrow = X + (size_t)(row0 + wv * 16 + li) * D_;

    for (int k0 = 0; k0 < D_; k0 += 32) {
        f32x4 a0 = *reinterpret_cast<const f32x4*>(Xrow + k0 + g * 8);
        f32x4 a1 = *reinterpret_cast<const f32x4*>(Xrow + k0 + g * 8 + 4);
        f16x8 af;
        for (int j = 0; j < 4; ++j) { af[j] = (f16)a0[j]; af[4 + j] = (f16)a1[j]; }
        for (int fc = 0; fc < 16; ++fc) {
            f16x8 bf = *reinterpret_cast<const f16x8*>(
                WT + (size_t)(c0 + fc * 16 + li) * D_ + k0 + g * 8);
            acc[fc] = __builtin_amdgcn_mfma_f32_16x16x32_f16(af, bf, acc[fc], 0, 0, 0);
        }
    }
    const int b = row0 >> 10;
    const int nloc = (row0 & 1023) + wv * 16 + g * 4;
    for (int fc = 0; fc < 16; ++fc) {
        int cw = cw0 + fc * 16 + li;
        int h = cw >> 6, dk = cw & 63;
        if (m < 2) {
            f16* dst = (m == 0 ? Qh : Kh) + ((size_t)(b * H_ + h) * N_ + nloc) * 64 + dk;
            for (int j = 0; j < 4; ++j) dst[(size_t)j * 64] = (f16)acc[fc][j];
        } else {
            f16x4 v4;
            for (int j = 0; j < 4; ++j) v4[j] = (f16)acc[fc][j];
            *reinterpret_cast<f16x4*>(Vt + ((size_t)(b * H_ + h) * 64 + dk) * N_ + nloc) = v4;
        }
    }
}

// ---------------------------------------------------------------------------
// Kernel 2: flash attention per (b, h, 64-row s-tile).  4 independent waves.
// Mask from 1 MB bitmask (L2-resident); next-tile mask/dw prefetched.
// ---------------------------------------------------------------------------
__global__ __launch_bounds__(256) void attn_kernel(
    const f16* __restrict__ Qh, const f16* __restrict__ Kh,
    const f16* __restrict__ Vt,
    const ull* __restrict__ bm, const float* __restrict__ dw,
    f16* __restrict__ AO)
{
    __shared__ f16 Ps[4][16][72];
    const int tid = threadIdx.x;
    const int wv = tid >> 6, lane = tid & 63;
    const int g = lane >> 4, li = lane & 15;
    const int bid = blockIdx.x;
    const int st = bid & 15, h = (bid >> 4) & 7, b = bid >> 7;
    const int s0 = st * 64 + wv * 16;

    const f16* Qbase = Qh + (size_t)(b * H_ + h) * N_ * 64;
    const f16* Kbase = Kh + (size_t)(b * H_ + h) * N_ * 64;
    const f16* Vbase = Vt + (size_t)(b * H_ + h) * 64 * N_;
    const ull* bmb = bm + (size_t)b * 16 * N_;
    const float* dwb = dw + b * N_;

    f16x8 qf[2];
    qf[0] = *reinterpret_cast<const f16x8*>(Qbase + (size_t)(s0 + li) * 64 + g * 8);
    qf[1] = *reinterpret_cast<const f16x8*>(Qbase + (size_t)(s0 + li) * 64 + 32 + g * 8);

    f32x4 of[4] = {};
    float m_run[4], l_run[4];
    for (int j = 0; j < 4; ++j) { m_run[j] = -1e30f; l_run[j] = 0.f; }

    // preload tile 0 mask words + dw
    ull2 w01 = *reinterpret_cast<const ull2*>(bmb + s0 + g * 4);
    ull2 w23 = *reinterpret_cast<const ull2*>(bmb + s0 + g * 4 + 2);
    float dwc[4];
    for (int fc = 0; fc < 4; ++fc) dwc[fc] = dwb[fc * 16 + li];

    for (int tt = 0; tt < 16; ++tt) {
        const int t0 = tt * 64;
        f32x4 s[4] = {};
        for (int fc = 0; fc < 4; ++fc) {
            const f16* kp = Kbase + (size_t)(t0 + fc * 16 + li) * 64 + g * 8;
            f16x8 kf0 = *reinterpret_cast<const f16x8*>(kp);
            f16x8 kf1 = *reinterpret_cast<const f16x8*>(kp + 32);
            s[fc] = __builtin_amdgcn_mfma_f32_16x16x32_f16(qf[0], kf0, s[fc], 0, 0, 0);
            s[fc] = __builtin_amdgcn_mfma_f32_16x16x32_f16(qf[1], kf1, s[fc], 0, 0, 0);
        }
        // prefetch next tile's mask words + dw
        const int tn = (tt + 1) & 15;
        ull2 nw01 = *reinterpret_cast<const ull2*>(bmb + tn * N_ + s0 + g * 4);
        ull2 nw23 = *reinterpret_cast<const ull2*>(bmb + tn * N_ + s0 + g * 4 + 2);
        float ndw[4];
        for (int fc = 0; fc < 4; ++fc) ndw[fc] = dwb[tn * 64 + fc * 16 + li];

        // logits = (S/8 + (1-m)*NEG) * dw[t];  C layout: row g*4+j, col li
        ull wsh[4];
        wsh[0] = w01.x >> li; wsh[1] = w01.y >> li;
        wsh[2] = w23.x >> li; wsh[3] = w23.y >> li;

        float pj[4][4];
        float mt[4] = {-1e30f, -1e30f, -1e30f, -1e30f};
        for (int fc = 0; fc < 4; ++fc) {
            float dwv = dwc[fc];
            for (int j = 0; j < 4; ++j) {
                float bias = ((wsh[j] >> (fc * 16)) & 1ull) ? 0.0f : -1.0e9f;
                float lg = (s[fc][j] * 0.125f + bias) * dwv;
                pj[fc][j] = lg;
                mt[j] = fmaxf(mt[j], lg);
            }
        }
        for (int j = 0; j < 4; ++j) {
            mt[j] = fmaxf(mt[j], __shfl_xor(mt[j], 1));
            mt[j] = fmaxf(mt[j], __shfl_xor(mt[j], 2));
            mt[j] = fmaxf(mt[j], __shfl_xor(mt[j], 4));
            mt[j] = fmaxf(mt[j], __shfl_xor(mt[j], 8));
        }
        float alpha[4];
        for (int j = 0; j < 4; ++j) {
            float mn = fmaxf(m_run[j], mt[j]);
            alpha[j] = __expf(m_run[j] - mn);
            m_run[j] = mn;
        }
        float rs[4] = {0.f, 0.f, 0.f, 0.f};
        for (int fc = 0; fc < 4; ++fc)
            for (int j = 0; j < 4; ++j) {
                float p = __expf(pj[fc][j] - m_run[j]);
                pj[fc][j] = p;
                rs[j] += p;
            }
        for (int j = 0; j < 4; ++j) {
            rs[j] += __shfl_xor(rs[j], 1);
            rs[j] += __shfl_xor(rs[j], 2);
            rs[j] += __shfl_xor(rs[j], 4);
            rs[j] += __shfl_xor(rs[j], 8);
            l_run[j] = l_run[j] * alpha[j] + rs[j];
        }
        for (int fc = 0; fc < 4; ++fc)
            for (int j = 0; j < 4; ++j) of[fc][j] *= alpha[j];
        // P -> per-wave LDS (C layout) -> A fragments (row=li, k=t_local)
        for (int fc = 0; fc < 4; ++fc)
            for (int j = 0; j < 4; ++j)
                Ps[wv][g * 4 + j][fc * 16 + li] = (f16)pj[fc][j];
        f16x8 pf0 = *reinterpret_cast<const f16x8*>(&Ps[wv][li][g * 8]);
        f16x8 pf1 = *reinterpret_cast<const f16x8*>(&Ps[wv][li][32 + g * 8]);
        for (int fc = 0; fc < 4; ++fc) {
            const f16* vp = Vbase + (size_t)(fc * 16 + li) * N_ + t0 + g * 8;
            f16x8 vf0 = *reinterpret_cast<const f16x8*>(vp);
            f16x8 vf1 = *reinterpret_cast<const f16x8*>(vp + 32);
            of[fc] = __builtin_amdgcn_mfma_f32_16x16x32_f16(pf0, vf0, of[fc], 0, 0, 0);
            of[fc] = __builtin_amdgcn_mfma_f32_16x16x32_f16(pf1, vf1, of[fc], 0, 0, 0);
        }
        w01 = nw01; w23 = nw23;
        for (int fc = 0; fc < 4; ++fc) dwc[fc] = ndw[fc];
    }
    for (int j = 0; j < 4; ++j) {
        float inv = 1.f / l_run[j];
        int srow = s0 + g * 4 + j;
        f16* dst = AO + ((size_t)b * N_ + srow) * HD_ + h * 64;
        for (int fc = 0; fc < 4; ++fc)
            dst[fc * 16 + li] = (f16)(of[fc][j] * inv);
    }
}

// ---------------------------------------------------------------------------
// Kernel 3: out = AO(8192,512)@Wo + bo, no LDS; B-fragments from WToT f16.
// Block: 64 rows x 64 cols, 4 waves; wave = 16 rows x 64 cols.
// ---------------------------------------------------------------------------
__global__ __launch_bounds__(256) void proj_kernel(
    const f16* __restrict__ AO, const f16* __restrict__ WToT,
    const float* __restrict__ bo, float* __restrict__ out)
{
    const int tid = threadIdx.x;
    const int wv = tid >> 6, lane = tid & 63;
    const int g = lane >> 4, li = lane & 15;
    const int row0 = blockIdx.x * 64, c0 = blockIdx.y * 64;

    f32x4 acc[4] = {};
    const f16* Arow = AO + (size_t)(row0 + wv * 16 + li) * HD_;

    for (int k0 = 0; k0 < HD_; k0 += 32) {
        f16x8 af = *reinterpret_cast<const f16x8*>(Arow + k0 + g * 8);
        for (int fc = 0; fc < 4; ++fc) {
            f16x8 bf = *reinterpret_cast<const f16x8*>(
                WToT + (size_t)(c0 + fc * 16 + li) * HD_ + k0 + g * 8);
            acc[fc] = __builtin_amdgcn_mfma_f32_16x16x32_f16(af, bf, acc[fc], 0, 0, 0);
        }
    }
    for (int fc = 0; fc < 4; ++fc) {
        int c = c0 + fc * 16 + li;
        float bias = bo[c];
        for (int j = 0; j < 4; ++j) {
            int r = row0 + wv * 16 + g * 4 + j;
            out[(size_t)r * D_ + c] = acc[fc][j] + bias;
        }
    }
}

extern "C" void kernel_launch(void* const* d_in, const int* in_sizes, int n_in,
                              void* d_out, int out_size, void* d_ws, size_t ws_size,
                              hipStream_t stream) {
    const float* X    = (const float*)d_in[0];
    const float* mask = (const float*)d_in[1];
    const float* dwv  = (const float*)d_in[2];
    const float* Wq   = (const float*)d_in[3];
    const float* Wk   = (const float*)d_in[4];
    const float* Wv   = (const float*)d_in[5];
    const float* Wo   = (const float*)d_in[6];
    const float* bo   = (const float*)d_in[7];
    float* out = (float*)d_out;

    // ws layout (32 MB total, unchanged budget):
    const size_t per = (size_t)B_ * H_ * N_ * 64;   // 4M halves each
    f16* Qh = (f16*)d_ws;
    f16* Kh = Qh + per;
    f16* Vt = Kh + per;
    f16* AO = Vt + per;
    f16* WToT = (f16*)d_ws;   // overlaps Qh; built AFTER attn (Qh dead by then)

    // d_out doubles as early scratch (fully overwritten by proj at the end):
    //   [0, 1MB)       bmT  u64[8][16][1024]
    //   [1MB, 1.75MB)  WTqkv f16[1536][256]
    ull* bmT   = (ull*)d_out;
    f16* WTqkv = (f16*)((char*)d_out + (1u << 20));

    pack_mask_kernel<<<dim3(2048), 256, 0, stream>>>(mask, bmT);
    wconv_qkv_kernel<<<dim3(1536), 256, 0, stream>>>(Wq, Wk, Wv, WTqkv);
    qkv_kernel<<<dim3(128, 6), 256, 0, stream>>>(X, WTqkv, Qh, Kh, Vt);
    attn_kernel<<<dim3(1024), 256, 0, stream>>>(Qh, Kh, Vt, bmT, dwv, AO);
    wconv_o_kernel<<<dim3(256), 256, 0, stream>>>(Wo, WToT);
    proj_kernel<<<dim3(128, 4), 256, 0, stream>>>(AO, WToT, bo, out);
}

// Round 3
// 328.544 us; speedup vs baseline: 1.1537x; 1.1537x over previous
//
#include <hip/hip_runtime.h>
#include <hip/hip_bf16.h>
#include <hip/hip_fp16.h>

#define B_ 8
#define N_ 1024
#define D_ 256
#define H_ 8
#define HD_ 512   // H_*64

typedef _Float16 f16;
typedef _Float16 f16x8 __attribute__((ext_vector_type(8)));
typedef _Float16 f16x4 __attribute__((ext_vector_type(4)));
typedef float f32x4 __attribute__((ext_vector_type(4)));
typedef unsigned long long ull;
typedef unsigned long long ull2 __attribute__((ext_vector_type(2)));

// ---------------------------------------------------------------------------
// Pre-kernel A: bit-pack edge mask.  mask (B,N,N) f32 -> bmT[b][tt][row] u64
// bit t of bmT[b][tt][row] = (mask[b][row][tt*64+t] != 0)
// ---------------------------------------------------------------------------
__global__ __launch_bounds__(256) void pack_mask_kernel(
    const float* __restrict__ mask, ull* __restrict__ bmT)
{
    const int wv = threadIdx.x >> 6, lane = threadIdx.x & 63;
    const int r = blockIdx.x * 4 + wv;          // 0..8191
    const int b = r >> 10, n = r & 1023;
    const float* row = mask + ((size_t)b * N_ + n) * N_;
    for (int tt = 0; tt < 16; ++tt) {
        float v = row[tt * 64 + lane];
        ull m = __ballot(v != 0.0f);
        if (lane == 0) bmT[((size_t)b * 16 + tt) * N_ + n] = m;
    }
}

// Pre-kernel B: WTqkv[c][k] = f16( W{q|k|v}[k][c&511] ), c in [0,1536)
__global__ __launch_bounds__(256) void wconv_qkv_kernel(
    const float* __restrict__ Wq, const float* __restrict__ Wk,
    const float* __restrict__ Wv, f16* __restrict__ WT)
{
    const int c = blockIdx.x, k = threadIdx.x;
    const int m = c >> 9, cw = c & 511;
    const float* Wsel = (m == 0) ? Wq : (m == 1) ? Wk : Wv;
    WT[(size_t)c * D_ + k] = (f16)Wsel[(size_t)k * HD_ + cw];
}

// Pre-kernel C: WToT[c][k] = f16( Wo[k][c] )
__global__ __launch_bounds__(256) void wconv_o_kernel(
    const float* __restrict__ Wo, f16* __restrict__ WToT)
{
    const int c = blockIdx.x;
    for (int k = threadIdx.x; k < HD_; k += 256)
        WToT[(size_t)c * HD_ + k] = (f16)Wo[(size_t)k * D_ + c];
}

// ---------------------------------------------------------------------------
// Kernel 1: fused QKV projection.  Block = 16 rows x 256 cols, 4 waves;
// wave = 16 rows x 64 cols, K=256.  12288 waves total (12/SIMD).
// ---------------------------------------------------------------------------
__global__ __launch_bounds__(256, 8) void qkv_kernel(
    const float* __restrict__ X, const f16* __restrict__ WT,
    f16* __restrict__ Qh, f16* __restrict__ Kh, f16* __restrict__ Vt)
{
    const int tid = threadIdx.x;
    const int wv = tid >> 6, lane = tid & 63;
    const int g = lane >> 4, li = lane & 15;
    const int row0 = blockIdx.x * 16;                 // 512 row tiles
    const int c0 = blockIdx.y * 256 + wv * 64;        // global col in [0,1536)
    const int m = c0 >> 9;                            // 0=Q,1=K,2=V
    const int cw0 = c0 & 511;

    f32x4 acc[4] = {};
    const float* Xrow = X + (size_t)(row0 + li) * D_;

    for (int k0 = 0; k0 < D_; k0 += 32) {
        f32x4 a0 = *reinterpret_cast<const f32x4*>(Xrow + k0 + g * 8);
        f32x4 a1 = *reinterpret_cast<const f32x4*>(Xrow + k0 + g * 8 + 4);
        f16x8 af;
        for (int j = 0; j < 4; ++j) { af[j] = (f16)a0[j]; af[4 + j] = (f16)a1[j]; }
        for (int fc = 0; fc < 4; ++fc) {
            f16x8 bf = *reinterpret_cast<const f16x8*>(
                WT + (size_t)(c0 + fc * 16 + li) * D_ + k0 + g * 8);
            acc[fc] = __builtin_amdgcn_mfma_f32_16x16x32_f16(af, bf, acc[fc], 0, 0, 0);
        }
    }
    const int b = row0 >> 10;
    const int nloc = (row0 & 1023) + g * 4;
    for (int fc = 0; fc < 4; ++fc) {
        int cw = cw0 + fc * 16 + li;
        int h = cw >> 6, dk = cw & 63;
        if (m < 2) {
            f16* dst = (m == 0 ? Qh : Kh) + ((size_t)(b * H_ + h) * N_ + nloc) * 64 + dk;
            for (int j = 0; j < 4; ++j) dst[(size_t)j * 64] = (f16)acc[fc][j];
        } else {
            f16x4 v4;
            for (int j = 0; j < 4; ++j) v4[j] = (f16)acc[fc][j];
            *reinterpret_cast<f16x4*>(Vt + ((size_t)(b * H_ + h) * 64 + dk) * N_ + nloc) = v4;
        }
    }
}

// ---------------------------------------------------------------------------
// Kernel 2: flash attention.  XCD-swizzled so each XCD owns one batch
// (Q+K+V+bitmask ~3.2 MB -> L2-resident).  K double-buffered in registers.
// ---------------------------------------------------------------------------
__global__ __launch_bounds__(256, 4) void attn_kernel(
    const f16* __restrict__ Qh, const f16* __restrict__ Kh,
    const f16* __restrict__ Vt,
    const ull* __restrict__ bm, const float* __restrict__ dw,
    f16* __restrict__ AO)
{
    __shared__ f16 Ps[4][16][72];
    const int tid = threadIdx.x;
    const int wv = tid >> 6, lane = tid & 63;
    const int g = lane >> 4, li = lane & 15;
    // XCD swizzle: physical round-robin (%8) -> logical chunks of 128,
    // so each XCD processes exactly one batch b.
    const int bid = (blockIdx.x & 7) * 128 + (blockIdx.x >> 3);
    const int st = bid & 15, h = (bid >> 4) & 7, b = bid >> 7;
    const int s0 = st * 64 + wv * 16;

    const f16* Qbase = Qh + (size_t)(b * H_ + h) * N_ * 64;
    const f16* Kbase = Kh + (size_t)(b * H_ + h) * N_ * 64;
    const f16* Vbase = Vt + (size_t)(b * H_ + h) * 64 * N_;
    const ull* bmb = bm + (size_t)b * 16 * N_;
    const float* dwb = dw + b * N_;

    f16x8 qf[2];
    qf[0] = *reinterpret_cast<const f16x8*>(Qbase + (size_t)(s0 + li) * 64 + g * 8);
    qf[1] = *reinterpret_cast<const f16x8*>(Qbase + (size_t)(s0 + li) * 64 + 32 + g * 8);

    f32x4 of[4] = {};
    float m_run[4], l_run[4];
    for (int j = 0; j < 4; ++j) { m_run[j] = -1e30f; l_run[j] = 0.f; }

    // K register double-buffer
    f16x8 ka[4], kb[4];
    for (int fc = 0; fc < 4; ++fc) {
        const f16* kp = Kbase + (size_t)(fc * 16 + li) * 64 + g * 8;
        ka[fc] = *reinterpret_cast<const f16x8*>(kp);
        kb[fc] = *reinterpret_cast<const f16x8*>(kp + 32);
    }
    // tile-0 mask words + dw
    ull2 w01 = *reinterpret_cast<const ull2*>(bmb + s0 + g * 4);
    ull2 w23 = *reinterpret_cast<const ull2*>(bmb + s0 + g * 4 + 2);
    float dwc[4];
    for (int fc = 0; fc < 4; ++fc) dwc[fc] = dwb[fc * 16 + li];

    #pragma unroll 2
    for (int tt = 0; tt < 16; ++tt) {
        const int t0 = tt * 64;
        f32x4 s[4] = {};
        for (int fc = 0; fc < 4; ++fc) {
            s[fc] = __builtin_amdgcn_mfma_f32_16x16x32_f16(qf[0], ka[fc], s[fc], 0, 0, 0);
            s[fc] = __builtin_amdgcn_mfma_f32_16x16x32_f16(qf[1], kb[fc], s[fc], 0, 0, 0);
        }
        // prefetch next tile's K fragments (overlaps softmax below)
        const int tn = (tt + 1) & 15;
        f16x8 na[4], nb[4];
        for (int fc = 0; fc < 4; ++fc) {
            const f16* kp = Kbase + (size_t)(tn * 64 + fc * 16 + li) * 64 + g * 8;
            na[fc] = *reinterpret_cast<const f16x8*>(kp);
            nb[fc] = *reinterpret_cast<const f16x8*>(kp + 32);
        }
        ull2 nw01 = *reinterpret_cast<const ull2*>(bmb + tn * N_ + s0 + g * 4);
        ull2 nw23 = *reinterpret_cast<const ull2*>(bmb + tn * N_ + s0 + g * 4 + 2);
        float ndw[4];
        for (int fc = 0; fc < 4; ++fc) ndw[fc] = dwb[tn * 64 + fc * 16 + li];

        // logits in place: s[fc][j] = (S/8 + (1-m)*NEG) * dw[t]
        ull wsh[4];
        wsh[0] = w01.x >> li; wsh[1] = w01.y >> li;
        wsh[2] = w23.x >> li; wsh[3] = w23.y >> li;

        float mt[4] = {-1e30f, -1e30f, -1e30f, -1e30f};
        for (int fc = 0; fc < 4; ++fc) {
            float dwv = dwc[fc];
            for (int j = 0; j < 4; ++j) {
                float bias = ((wsh[j] >> (fc * 16)) & 1ull) ? 0.0f : -1.0e9f;
                float lg = (s[fc][j] * 0.125f + bias) * dwv;
                s[fc][j] = lg;
                mt[j] = fmaxf(mt[j], lg);
            }
        }
        for (int j = 0; j < 4; ++j) {
            mt[j] = fmaxf(mt[j], __shfl_xor(mt[j], 1));
            mt[j] = fmaxf(mt[j], __shfl_xor(mt[j], 2));
            mt[j] = fmaxf(mt[j], __shfl_xor(mt[j], 4));
            mt[j] = fmaxf(mt[j], __shfl_xor(mt[j], 8));
        }
        float alpha[4];
        for (int j = 0; j < 4; ++j) {
            float mn = fmaxf(m_run[j], mt[j]);
            alpha[j] = __expf(m_run[j] - mn);
            m_run[j] = mn;
        }
        float rs[4] = {0.f, 0.f, 0.f, 0.f};
        for (int fc = 0; fc < 4; ++fc)
            for (int j = 0; j < 4; ++j) {
                float p = __expf(s[fc][j] - m_run[j]);
                s[fc][j] = p;
                rs[j] += p;
            }
        for (int j = 0; j < 4; ++j) {
            rs[j] += __shfl_xor(rs[j], 1);
            rs[j] += __shfl_xor(rs[j], 2);
            rs[j] += __shfl_xor(rs[j], 4);
            rs[j] += __shfl_xor(rs[j], 8);
            l_run[j] = l_run[j] * alpha[j] + rs[j];
        }
        for (int fc = 0; fc < 4; ++fc)
            for (int j = 0; j < 4; ++j) of[fc][j] *= alpha[j];
        // P -> per-wave LDS (C layout) -> A fragments (row=li, k=t_local)
        for (int fc = 0; fc < 4; ++fc)
            for (int j = 0; j < 4; ++j)
                Ps[wv][g * 4 + j][fc * 16 + li] = (f16)s[fc][j];
        f16x8 pf0 = *reinterpret_cast<const f16x8*>(&Ps[wv][li][g * 8]);
        f16x8 pf1 = *reinterpret_cast<const f16x8*>(&Ps[wv][li][32 + g * 8]);
        for (int fc = 0; fc < 4; ++fc) {
            const f16* vp = Vbase + (size_t)(fc * 16 + li) * N_ + t0 + g * 8;
            f16x8 vf0 = *reinterpret_cast<const f16x8*>(vp);
            f16x8 vf1 = *reinterpret_cast<const f16x8*>(vp + 32);
            of[fc] = __builtin_amdgcn_mfma_f32_16x16x32_f16(pf0, vf0, of[fc], 0, 0, 0);
            of[fc] = __builtin_amdgcn_mfma_f32_16x16x32_f16(pf1, vf1, of[fc], 0, 0, 0);
        }
        for (int fc = 0; fc < 4; ++fc) { ka[fc] = na[fc]; kb[fc] = nb[fc]; }
        w01 = nw01; w23 = nw23;
        for (int fc = 0; fc < 4; ++fc) dwc[fc] = ndw[fc];
    }
    for (int j = 0; j < 4; ++j) {
        float inv = 1.f / l_run[j];
        int srow = s0 + g * 4 + j;
        f16* dst = AO + ((size_t)b * N_ + srow) * HD_ + h * 64;
        for (int fc = 0; fc < 4; ++fc)
            dst[fc * 16 + li] = (f16)(of[fc][j] * inv);
    }
}

// ---------------------------------------------------------------------------
// Kernel 3: out = AO @ Wo + bo.  Wave = 16 rows x 16 cols, K=512.
// Block = 16 rows x 64 cols (4 waves).  8192 waves (8/SIMD).
// ---------------------------------------------------------------------------
__global__ __launch_bounds__(256, 8) void proj_kernel(
    const f16* __restrict__ AO, const f16* __restrict__ WToT,
    const float* __restrict__ bo, float* __restrict__ out)
{
    const int tid = threadIdx.x;
    const int wv = tid >> 6, lane = tid & 63;
    const int g = lane >> 4, li = lane & 15;
    const int row0 = blockIdx.x * 16;                // 512 row tiles
    const int c0 = blockIdx.y * 64 + wv * 16;        // col in [0,256)

    f32x4 acc = {};
    const f16* Arow = AO + (size_t)(row0 + li) * HD_;
    const f16* Brow = WToT + (size_t)(c0 + li) * HD_;

    for (int k0 = 0; k0 < HD_; k0 += 32) {
        f16x8 af = *reinterpret_cast<const f16x8*>(Arow + k0 + g * 8);
        f16x8 bf = *reinterpret_cast<const f16x8*>(Brow + k0 + g * 8);
        acc = __builtin_amdgcn_mfma_f32_16x16x32_f16(af, bf, acc, 0, 0, 0);
    }
    const int c = c0 + li;
    const float bias = bo[c];
    for (int j = 0; j < 4; ++j)
        out[(size_t)(row0 + g * 4 + j) * D_ + c] = acc[j] + bias;
}

extern "C" void kernel_launch(void* const* d_in, const int* in_sizes, int n_in,
                              void* d_out, int out_size, void* d_ws, size_t ws_size,
                              hipStream_t stream) {
    const float* X    = (const float*)d_in[0];
    const float* mask = (const float*)d_in[1];
    const float* dwv  = (const float*)d_in[2];
    const float* Wq   = (const float*)d_in[3];
    const float* Wk   = (const float*)d_in[4];
    const float* Wv   = (const float*)d_in[5];
    const float* Wo   = (const float*)d_in[6];
    const float* bo   = (const float*)d_in[7];
    float* out = (float*)d_out;

    const size_t per = (size_t)B_ * H_ * N_ * 64;   // 4M halves each
    f16* Qh = (f16*)d_ws;
    f16* Kh = Qh + per;
    f16* Vt = Kh + per;
    f16* AO = Vt + per;
    f16* WToT = (f16*)d_ws;   // overlaps Qh; built AFTER attn (Qh dead)

    // d_out doubles as early scratch (overwritten by proj at the end):
    ull* bmT   = (ull*)d_out;                          // 1 MB
    f16* WTqkv = (f16*)((char*)d_out + (1u << 20));    // 0.75 MB

    pack_mask_kernel<<<dim3(2048), 256, 0, stream>>>(mask, bmT);
    wconv_qkv_kernel<<<dim3(1536), 256, 0, stream>>>(Wq, Wk, Wv, WTqkv);
    qkv_kernel<<<dim3(512, 6), 256, 0, stream>>>(X, WTqkv, Qh, Kh, Vt);
    attn_kernel<<<dim3(1024), 256, 0, stream>>>(Qh, Kh, Vt, bmT, dwv, AO);
    wconv_o_kernel<<<dim3(256), 256, 0, stream>>>(Wo, WToT);
    proj_kernel<<<dim3(512, 4), 256, 0, stream>>>(AO, WToT, bo, out);
}

// Round 4
// 196.923 us; speedup vs baseline: 1.9249x; 1.6684x over previous
//
#include <hip/hip_runtime.h>
#include <hip/hip_bf16.h>
#include <hip/hip_fp16.h>
#include <cstdint>

#define B_ 8
#define N_ 1024
#define D_ 256
#define H_ 8
#define HD_ 512   // H_*64

typedef _Float16 f16;
typedef _Float16 f16x8 __attribute__((ext_vector_type(8)));
typedef _Float16 f16x4 __attribute__((ext_vector_type(4)));
typedef float f32x4 __attribute__((ext_vector_type(4)));
typedef unsigned long long ull;
typedef unsigned long long ull2 __attribute__((ext_vector_type(2)));

// async global->LDS, 16B per lane.  dest = wave-uniform base + lane*16.
__device__ __forceinline__ void gload16(const void* g, void* l) {
    __builtin_amdgcn_global_load_lds(
        (const __attribute__((address_space(1))) unsigned int*)(uintptr_t)g,
        (__attribute__((address_space(3))) unsigned int*)(uintptr_t)l,
        16, 0, 0);
}

// ---------------------------------------------------------------------------
// Pre-kernel A: bit-pack edge mask.  mask (B,N,N) f32 -> bmT[b][tt][row] u64
// ---------------------------------------------------------------------------
__global__ __launch_bounds__(256) void pack_mask_kernel(
    const float* __restrict__ mask, ull* __restrict__ bmT)
{
    const int wv = threadIdx.x >> 6, lane = threadIdx.x & 63;
    const int r = blockIdx.x * 4 + wv;
    const int b = r >> 10, n = r & 1023;
    const float* row = mask + ((size_t)b * N_ + n) * N_;
    for (int tt = 0; tt < 16; ++tt) {
        float v = row[tt * 64 + lane];
        ull m = __ballot(v != 0.0f);
        if (lane == 0) bmT[((size_t)b * 16 + tt) * N_ + n] = m;
    }
}

// ---------------------------------------------------------------------------
// Pre-kernel B: WTqkv[c][k] = f16(W{q|k|v}[k][c&511]) via LDS transpose.
// Grid (24 c-tiles, 4 k-tiles), 64x64 tiles.
// ---------------------------------------------------------------------------
__global__ __launch_bounds__(256) void wconv_qkv_kernel(
    const float* __restrict__ Wq, const float* __restrict__ Wk,
    const float* __restrict__ Wv, f16* __restrict__ WT)
{
    __shared__ float Ws[64][65];
    const int tid = threadIdx.x;
    const int c0 = blockIdx.x * 64, k0 = blockIdx.y * 64;
    const int m = c0 >> 9, cw0 = c0 & 511;
    const float* Wsel = (m == 0) ? Wq : (m == 1) ? Wk : Wv;
    const int rr = tid >> 6, cc = tid & 63;
    for (int i = 0; i < 16; ++i)
        Ws[i * 4 + rr][cc] = Wsel[(size_t)(k0 + i * 4 + rr) * HD_ + cw0 + cc];
    __syncthreads();
    for (int i = 0; i < 16; ++i)
        WT[(size_t)(c0 + i * 4 + rr) * D_ + k0 + cc] = (f16)Ws[cc][i * 4 + rr];
}

// Pre-kernel C: WToT[c][k] = f16(Wo[k][c]) via LDS transpose. Grid (4, 8).
__global__ __launch_bounds__(256) void wconv_o_kernel(
    const float* __restrict__ Wo, f16* __restrict__ WToT)
{
    __shared__ float Ws[64][65];
    const int tid = threadIdx.x;
    const int c0 = blockIdx.x * 64, k0 = blockIdx.y * 64;
    const int rr = tid >> 6, cc = tid & 63;
    for (int i = 0; i < 16; ++i)
        Ws[i * 4 + rr][cc] = Wo[(size_t)(k0 + i * 4 + rr) * D_ + c0 + cc];
    __syncthreads();
    for (int i = 0; i < 16; ++i)
        WToT[(size_t)(c0 + i * 4 + rr) * HD_ + k0 + cc] = (f16)Ws[cc][i * 4 + rr];
}

// ---------------------------------------------------------------------------
// Kernel 1: fused QKV.  Block 64 rows x 256 cols, 4 waves (16 rows x 256 each).
// W-tile [256 c][64 k] f16 staged via global_load_lds, XOR-swizzled 16B chunks.
// ---------------------------------------------------------------------------
__global__ __launch_bounds__(256, 4) void qkv_kernel(
    const float* __restrict__ X, const f16* __restrict__ WT,
    f16* __restrict__ Qh, f16* __restrict__ Kh, f16* __restrict__ Vt)
{
    __shared__ f16 Wsh[256 * 64];   // 32 KB: row c = 8 chunks of 16B, swizzled
    const int tid = threadIdx.x;
    const int wv = tid >> 6, lane = tid & 63;
    const int g = lane >> 4, li = lane & 15;
    const int row0 = blockIdx.x * 64;
    const int c0 = blockIdx.y * 256;
    const int m = c0 >> 9, cw0 = c0 & 511;

    f32x4 acc[16] = {};
    const float* Xrow = X + (size_t)(row0 + wv * 16 + li) * D_;

    for (int ks = 0; ks < 4; ++ks) {
        __syncthreads();   // previous compute done before overwrite
        for (int i = 0; i < 8; ++i) {
            const int idx = i * 256 + wv * 64 + lane;
            const int c = idx >> 3, ch = idx & 7;
            const f16* src = WT + (size_t)(c0 + c) * D_ + ks * 64 + ((ch ^ (c & 7)) * 8);
            gload16(src, &Wsh[(i * 256 + wv * 64) * 8]);
        }
        __syncthreads();   // drain DMA
        for (int kk = 0; kk < 2; ++kk) {
            const int k0 = ks * 64 + kk * 32;
            f32x4 a0 = *reinterpret_cast<const f32x4*>(Xrow + k0 + g * 8);
            f32x4 a1 = *reinterpret_cast<const f32x4*>(Xrow + k0 + g * 8 + 4);
            f16x8 af;
            for (int j = 0; j < 4; ++j) { af[j] = (f16)a0[j]; af[4 + j] = (f16)a1[j]; }
            for (int fc = 0; fc < 16; ++fc) {
                const int c = fc * 16 + li;
                const int chn = (kk * 4 + g) ^ (c & 7);
                f16x8 bf = *reinterpret_cast<const f16x8*>(&Wsh[c * 64 + chn * 8]);
                acc[fc] = __builtin_amdgcn_mfma_f32_16x16x32_f16(af, bf, acc[fc], 0, 0, 0);
            }
        }
    }
    const int b = row0 >> 10;
    const int nloc = (row0 & 1023) + wv * 16 + g * 4;
    for (int fc = 0; fc < 16; ++fc) {
        int cw = cw0 + fc * 16 + li;
        int h = cw >> 6, dk = cw & 63;
        if (m < 2) {
            f16* dst = (m == 0 ? Qh : Kh) + ((size_t)(b * H_ + h) * N_ + nloc) * 64 + dk;
            for (int j = 0; j < 4; ++j) dst[(size_t)j * 64] = (f16)acc[fc][j];
        } else {
            f16x4 v4;
            for (int j = 0; j < 4; ++j) v4[j] = (f16)acc[fc][j];
            *reinterpret_cast<f16x4*>(Vt + ((size_t)(b * H_ + h) * 64 + dk) * N_ + nloc) = v4;
        }
    }
}

// ---------------------------------------------------------------------------
// Kernel 2: flash attention.  K/V tiles LDS-shared across the block's 4 waves,
// double-buffered via global_load_lds (pre-swizzled source, swizzled ds_read).
// XCD-swizzled blockIdx.  LDS exactly 40 KB -> 4 blocks/CU.
// ---------------------------------------------------------------------------
__global__ __launch_bounds__(256, 4) void attn_kernel(
    const f16* __restrict__ Qh, const f16* __restrict__ Kh,
    const f16* __restrict__ Vt,
    const ull* __restrict__ bm, const float* __restrict__ dw,
    f16* __restrict__ AO)
{
    __shared__ f16 Ksh[2][4096];   // 64 rows x 8 chunks x 16B, swizzled
    __shared__ f16 Vsh[2][4096];
    __shared__ f16 Ps[4][1024];    // per-wave 16 x 64, swizzled
    const int tid = threadIdx.x;
    const int wv = tid >> 6, lane = tid & 63;
    const int g = lane >> 4, li = lane & 15;
    const int bid = (blockIdx.x & 7) * 128 + (blockIdx.x >> 3);
    const int st = bid & 15, h = (bid >> 4) & 7, b = bid >> 7;
    const int s0 = st * 64 + wv * 16;

    const f16* Qbase = Qh + (size_t)(b * H_ + h) * N_ * 64;
    const f16* Kbase = Kh + (size_t)(b * H_ + h) * N_ * 64;
    const f16* Vbase = Vt + (size_t)(b * H_ + h) * 64 * N_;
    const ull* bmb = bm + (size_t)b * 16 * N_;
    const float* dwb = dw + b * N_;

    f16x8 qf[2];
    qf[0] = *reinterpret_cast<const f16x8*>(Qbase + (size_t)(s0 + li) * 64 + g * 8);
    qf[1] = *reinterpret_cast<const f16x8*>(Qbase + (size_t)(s0 + li) * 64 + 32 + g * 8);

    f32x4 of[4] = {};
    float m_run[4], l_run[4];
    for (int j = 0; j < 4; ++j) { m_run[j] = -1e30f; l_run[j] = 0.f; }

    // stage tile tt of K and V into buffer bf (512 chunks each, 2/thread)
    auto stage = [&](int tt, int bf) {
        for (int i = 0; i < 2; ++i) {
            const int idx = i * 256 + wv * 64 + lane;
            const int row = idx >> 3, ch = idx & 7;
            const int sch = (ch ^ (row & 7)) * 8;
            const f16* ksrc = Kbase + (size_t)(tt * 64 + row) * 64 + sch;
            gload16(ksrc, &Ksh[bf][(i * 256 + wv * 64) * 8]);
            const f16* vsrc = Vbase + (size_t)row * N_ + tt * 64 + sch;
            gload16(vsrc, &Vsh[bf][(i * 256 + wv * 64) * 8]);
        }
    };

    stage(0, 0);
    __syncthreads();
    int cur = 0;

    for (int tt = 0; tt < 16; ++tt) {
        if (tt < 15) stage(tt + 1, cur ^ 1);   // async, drained by end barrier

        // mask words + dw for this tile (L2-resident, issue early)
        ull2 w01 = *reinterpret_cast<const ull2*>(bmb + tt * N_ + s0 + g * 4);
        ull2 w23 = *reinterpret_cast<const ull2*>(bmb + tt * N_ + s0 + g * 4 + 2);
        float dwc[4];
        for (int fc = 0; fc < 4; ++fc) dwc[fc] = dwb[tt * 64 + fc * 16 + li];

        f32x4 s[4] = {};
        for (int fc = 0; fc < 4; ++fc) {
            const int r = fc * 16 + li;
            const f16* kb_ = &Ksh[cur][r * 64];
            f16x8 kf0 = *reinterpret_cast<const f16x8*>(&kb_[(g ^ (r & 7)) * 8]);
            f16x8 kf1 = *reinterpret_cast<const f16x8*>(&kb_[((4 | g) ^ (r & 7)) * 8]);
            s[fc] = __builtin_amdgcn_mfma_f32_16x16x32_f16(qf[0], kf0, s[fc], 0, 0, 0);
            s[fc] = __builtin_amdgcn_mfma_f32_16x16x32_f16(qf[1], kf1, s[fc], 0, 0, 0);
        }
        // logits: (S/8 + (1-m)*NEG) * dw[t];  C layout row g*4+j, col li
        ull wsh[4];
        wsh[0] = w01.x >> li; wsh[1] = w01.y >> li;
        wsh[2] = w23.x >> li; wsh[3] = w23.y >> li;

        float mt[4] = {-1e30f, -1e30f, -1e30f, -1e30f};
        for (int fc = 0; fc < 4; ++fc) {
            float dwv = dwc[fc];
            for (int j = 0; j < 4; ++j) {
                float bias = ((wsh[j] >> (fc * 16)) & 1ull) ? 0.0f : -1.0e9f;
                float lg = (s[fc][j] * 0.125f + bias) * dwv;
                s[fc][j] = lg;
                mt[j] = fmaxf(mt[j], lg);
            }
        }
        for (int j = 0; j < 4; ++j) {
            mt[j] = fmaxf(mt[j], __shfl_xor(mt[j], 1));
            mt[j] = fmaxf(mt[j], __shfl_xor(mt[j], 2));
            mt[j] = fmaxf(mt[j], __shfl_xor(mt[j], 4));
            mt[j] = fmaxf(mt[j], __shfl_xor(mt[j], 8));
        }
        float alpha[4];
        for (int j = 0; j < 4; ++j) {
            float mn = fmaxf(m_run[j], mt[j]);
            alpha[j] = __expf(m_run[j] - mn);
            m_run[j] = mn;
        }
        float rs[4] = {0.f, 0.f, 0.f, 0.f};
        for (int fc = 0; fc < 4; ++fc)
            for (int j = 0; j < 4; ++j) {
                float p = __expf(s[fc][j] - m_run[j]);
                s[fc][j] = p;
                rs[j] += p;
            }
        for (int j = 0; j < 4; ++j) {
            rs[j] += __shfl_xor(rs[j], 1);
            rs[j] += __shfl_xor(rs[j], 2);
            rs[j] += __shfl_xor(rs[j], 4);
            rs[j] += __shfl_xor(rs[j], 8);
            l_run[j] = l_run[j] * alpha[j] + rs[j];
        }
        for (int fc = 0; fc < 4; ++fc)
            for (int j = 0; j < 4; ++j) of[fc][j] *= alpha[j];

        // P -> per-wave swizzled LDS -> A fragments
        {
            f16* psw = Ps[wv];
            for (int fc = 0; fc < 4; ++fc)
                for (int j = 0; j < 4; ++j) {
                    const int r = g * 4 + j, c = fc * 16 + li;
                    psw[r * 64 + (((c >> 3) ^ (r & 7)) * 8) + (c & 7)] = (f16)s[fc][j];
                }
            f16x8 pf0 = *reinterpret_cast<const f16x8*>(&psw[li * 64 + ((g ^ (li & 7)) * 8)]);
            f16x8 pf1 = *reinterpret_cast<const f16x8*>(&psw[li * 64 + (((4 | g) ^ (li & 7)) * 8)]);
            for (int fc = 0; fc < 4; ++fc) {
                const int r = fc * 16 + li;
                const f16* vb_ = &Vsh[cur][r * 64];
                f16x8 vf0 = *reinterpret_cast<const f16x8*>(&vb_[(g ^ (r & 7)) * 8]);
                f16x8 vf1 = *reinterpret_cast<const f16x8*>(&vb_[((4 | g) ^ (r & 7)) * 8]);
                of[fc] = __builtin_amdgcn_mfma_f32_16x16x32_f16(pf0, vf0, of[fc], 0, 0, 0);
                of[fc] = __builtin_amdgcn_mfma_f32_16x16x32_f16(pf1, vf1, of[fc], 0, 0, 0);
            }
        }
        __syncthreads();   // drains stage(tt+1) DMA + orders LDS buffer reuse
        cur ^= 1;
    }
    for (int j = 0; j < 4; ++j) {
        float inv = 1.f / l_run[j];
        int srow = s0 + g * 4 + j;
        f16* dst = AO + ((size_t)b * N_ + srow) * HD_ + h * 64;
        for (int fc = 0; fc < 4; ++fc)
            dst[fc * 16 + li] = (f16)(of[fc][j] * inv);
    }
}

// ---------------------------------------------------------------------------
// Kernel 3: out = AO @ Wo + bo.  Block 16 rows x 256 cols, 4 waves (16x64).
// A staged once in LDS (16 KB, swizzled); B from L2-resident WToT.
// ---------------------------------------------------------------------------
__global__ __launch_bounds__(256, 4) void proj_kernel(
    const f16* __restrict__ AO, const f16* __restrict__ WToT,
    const float* __restrict__ bo, float* __restrict__ out)
{
    __shared__ f16 Ash[16 * 512];   // 16 rows x 64 chunks x 16B, swizzled
    const int tid = threadIdx.x;
    const int wv = tid >> 6, lane = tid & 63;
    const int g = lane >> 4, li = lane & 15;
    const int row0 = blockIdx.x * 16;
    const int c0 = wv * 64;

    for (int i = 0; i < 4; ++i) {
        const int idx = i * 256 + wv * 64 + lane;
        const int r = idx >> 6, ch = idx & 63;
        const f16* src = AO + (size_t)(row0 + r) * HD_ + ((ch ^ (r & 7)) * 8);
        gload16(src, &Ash[(i * 256 + wv * 64) * 8]);
    }
    __syncthreads();

    f32x4 acc[4] = {};
    for (int k0 = 0; k0 < HD_; k0 += 32) {
        const int cb = k0 >> 3;
        f16x8 af = *reinterpret_cast<const f16x8*>(
            &Ash[li * HD_ + (((cb + g) ^ (li & 7)) * 8)]);
        for (int fc = 0; fc < 4; ++fc) {
            f16x8 bf = *reinterpret_cast<const f16x8*>(
                WToT + (size_t)(c0 + fc * 16 + li) * HD_ + k0 + g * 8);
            acc[fc] = __builtin_amdgcn_mfma_f32_16x16x32_f16(af, bf, acc[fc], 0, 0, 0);
        }
    }
    for (int fc = 0; fc < 4; ++fc) {
        const int c = c0 + fc * 16 + li;
        const float bias = bo[c];
        for (int j = 0; j < 4; ++j)
            out[(size_t)(row0 + g * 4 + j) * D_ + c] = acc[fc][j] + bias;
    }
}

extern "C" void kernel_launch(void* const* d_in, const int* in_sizes, int n_in,
                              void* d_out, int out_size, void* d_ws, size_t ws_size,
                              hipStream_t stream) {
    const float* X    = (const float*)d_in[0];
    const float* mask = (const float*)d_in[1];
    const float* dwv  = (const float*)d_in[2];
    const float* Wq   = (const float*)d_in[3];
    const float* Wk   = (const float*)d_in[4];
    const float* Wv   = (const float*)d_in[5];
    const float* Wo   = (const float*)d_in[6];
    const float* bo   = (const float*)d_in[7];
    float* out = (float*)d_out;

    const size_t per = (size_t)B_ * H_ * N_ * 64;   // 4M halves each
    f16* Qh = (f16*)d_ws;
    f16* Kh = Qh + per;
    f16* Vt = Kh + per;
    f16* AO = Vt + per;
    f16* WToT = (f16*)d_ws;   // overlaps Qh; built AFTER attn (Qh dead)

    ull* bmT   = (ull*)d_out;                          // 1 MB scratch in d_out
    f16* WTqkv = (f16*)((char*)d_out + (1u << 20));    // 0.75 MB

    pack_mask_kernel<<<dim3(2048), 256, 0, stream>>>(mask, bmT);
    wconv_qkv_kernel<<<dim3(24, 4), 256, 0, stream>>>(Wq, Wk, Wv, WTqkv);
    qkv_kernel<<<dim3(128, 6), 256, 0, stream>>>(X, WTqkv, Qh, Kh, Vt);
    attn_kernel<<<dim3(1024), 256, 0, stream>>>(Qh, Kh, Vt, bmT, dwv, AO);
    wconv_o_kernel<<<dim3(4, 8), 256, 0, stream>>>(Wo, WToT);
    proj_kernel<<<dim3(512, 1), 256, 0, stream>>>(AO, WToT, bo, out);
}